// Round 7
// baseline (462.121 us; speedup 1.0000x reference)
//
#include <hip/hip_runtime.h>

#define H 128          // hidden dim (fixed by problem)
#define CAP 64         // max edges per (rel,dst) bucket

typedef _Float16 f16x8 __attribute__((ext_vector_type(8)));
typedef _Float16 f16x4 __attribute__((ext_vector_type(4)));
typedef float    f32x4 __attribute__((ext_vector_type(4)));

// ---------------- edge bucketing: one pass, reused by both layers ----------------
__global__ __launch_bounds__(256) void hist_fill(const int* __restrict__ src,
    const int* __restrict__ dst, const int* __restrict__ et,
    int* __restrict__ cnt, int* __restrict__ elist, int E, int N)
{
    int e = blockIdx.x * 256 + threadIdx.x;
    if (e >= E) return;
    int s = src[e], d = dst[e], t = et[e];
    int b = t * N + d;
    int pos = atomicAdd(&cnt[b], 1);
    if (pos < CAP) elist[(size_t)b * CAP + pos] = s;
}

// ---------------- feature fp32 -> fp16, pure streaming ----------------------------
// Also a diagnostic: float4-copy pattern should run ~6.3 TB/s (m13 µbench). If
// this kernel crawls, the READ path itself is the pipeline's invariant wall.
__global__ __launch_bounds__(256) void cvt_feat(const float* __restrict__ A,
    _Float16* __restrict__ A16, long long total8)
{
    long long i = (long long)blockIdx.x * 256 + threadIdx.x;
    long long stride = (long long)gridDim.x * 256;
    for (; i < total8; i += stride) {
        float4 v0 = *(const float4*)(A + i * 8);
        float4 v1 = *(const float4*)(A + i * 8 + 4);
        f16x8 o;
        o[0] = (_Float16)v0.x; o[1] = (_Float16)v0.y;
        o[2] = (_Float16)v0.z; o[3] = (_Float16)v0.w;
        o[4] = (_Float16)v1.x; o[5] = (_Float16)v1.y;
        o[6] = (_Float16)v1.z; o[7] = (_Float16)v1.w;
        *(f16x8*)(A16 + i * 8) = o;
    }
}

// ---------------- weight prep ----------------
// wInT: packed MFMA-B-fragment order for gemm_big (proven layout).
// wcatT: [col][384] f16 = concat_k(W_root;W_0;W_1) transposed — B for gemm_cat.
__global__ __launch_bounds__(256) void prep_w(const float* __restrict__ w_in,
    const float* __restrict__ w_root, const float* __restrict__ w_rel,
    _Float16* __restrict__ wInT, _Float16* __restrict__ wcatT, int K)
{
    int idx = blockIdx.x * 256 + threadIdx.x;
    int tot1 = K * H;                                  // 98304
    if (idx < tot1) {
        int k = idx >> 7, c = idx & 127;               // coalesced read of w_in
        int o = ((k >> 3) << 10) + (c << 3) + (k & 7); // ((k/8)*H + c)*8 + k%8
        wInT[o] = (_Float16)w_in[idx];
    } else {
        int i2 = idx - tot1;                           // < 128*384 = 49152
        if (i2 < H * 384) {
            int c = i2 / 384, k = i2 - c * 384;
            float v;
            if (k < 128)      v = w_root[(size_t)k * H + c];
            else if (k < 256) v = w_rel[(size_t)(k - 128) * H + c];
            else              v = w_rel[(size_t)H * H + (size_t)(k - 256) * H + c];
            wcatT[i2] = (_Float16)v;
        }
    }
}

// wfin[m][k][c] = W_m @ w_out ; bfin = b_conv@Wo + bo. One THREAD per output
// element (r5 version ran 384 serial loops on 2 blocks = possible hidden tens
// of µs on 2 CUs; now 1155 threads across 5 blocks).
__global__ __launch_bounds__(256) void prep_fin(const float* __restrict__ w_root,
    const float* __restrict__ w_rel, const float* __restrict__ b_conv,
    const float* __restrict__ w_out, const float* __restrict__ b_out,
    float* __restrict__ wfin, float* __restrict__ bfin, int OUT)
{
    int idx = blockIdx.x * 256 + threadIdx.x;
    int nw = 3 * H * OUT;
    if (idx < nw) {
        int mk = idx / OUT, c = idx - mk * OUT;
        int m = mk >> 7, k = mk & 127;
        const float* W = (m == 0) ? w_root : (w_rel + (size_t)(m - 1) * H * H);
        float s = 0.f;
        for (int j = 0; j < H; j++)
            s += W[(size_t)k * H + j] * w_out[(size_t)j * OUT + c];
        wfin[(size_t)mk * OUT + c] = s;
    } else if (idx < nw + OUT) {
        int c = idx - nw;
        float s = b_out[c];
        for (int j = 0; j < H; j++) s += b_conv[j] * w_out[(size_t)j * OUT + c];
        bfin[c] = s;
    }
}

// ---------------- big MFMA GEMM v5: fp16 A, contiguous LDS staging ---------------
// X1 = fp16(leakyrelu(A16[M,768] @ W + b)). v4 structure (verified correct),
// A now fp16: per 128-k chunk each wave stages its 16 rows as 256B contiguous
// runs (4 rows per 1KB load instr), direct ds_write_b128 (no cvt). Half the
// staged bytes of v4 — tests the byte-proportional-wall model (95 -> ~50?).
__global__ __launch_bounds__(256, 3) void gemm_big(const _Float16* __restrict__ A16,
    const _Float16* __restrict__ WP, const float* __restrict__ bias,
    _Float16* __restrict__ C16, int M, int K, int ldc)
{
    __shared__ _Float16 As[2][8192];   // [buf][slot*512 + (row^(slot&7))*8]

    const int tid = threadIdx.x;
    const int w   = tid >> 6;
    const int l   = tid & 63;
    const int l15 = l & 15;
    const int q   = l >> 4;
    const int brow = blockIdx.x * 64;
    const int wr   = w * 16;

    // staging geometry: lane (r4 = l>>4, c16 = l&15); 4 instrs x 4 rows = 16 rows
    const int r4  = l >> 4;
    const int c16 = l & 15;                      // slot (8-col group in chunk)

    const _Float16* bp = WP + ((size_t)q * H + l15) * 8;

    float bj[8];
#pragma unroll
    for (int j = 0; j < 8; j++) bj[j] = bias[j * 16 + l15];

    f32x4 acc[8];
    const f32x4 z4 = {0.f, 0.f, 0.f, 0.f};
#pragma unroll
    for (int j = 0; j < 8; j++) acc[j] = z4;

    const int chunks = K / 128;                 // 6
    f16x8 st[4];

    // ---- prologue: stage chunk 0 ----
    {
        const _Float16* apc = A16 + c16 * 8;
#pragma unroll
        for (int i = 0; i < 4; i++) {
            int gr = brow + wr + r4 + i * 4; if (gr >= M) gr = M - 1;
            st[i] = *(const f16x8*)(apc + (size_t)gr * K);
        }
#pragma unroll
        for (int i = 0; i < 4; i++) {
            int row = wr + r4 + i * 4;
            *(f16x8*)&As[0][c16 * 512 + ((row ^ (c16 & 7)) << 3)] = st[i];
        }
    }
    __syncthreads();

    for (int c = 0; c < chunks; c++) {
        const bool more = (c + 1) < chunks;
        if (more) {
            const _Float16* apc = A16 + (c + 1) * 128 + c16 * 8;
#pragma unroll
            for (int i = 0; i < 4; i++) {
                int gr = brow + wr + r4 + i * 4; if (gr >= M) gr = M - 1;
                st[i] = *(const f16x8*)(apc + (size_t)gr * K);
            }
        }
        {
            const _Float16* __restrict__ buf = As[c & 1];
#pragma unroll
            for (int ks = 0; ks < 4; ks++) {
                const int sl = ks * 4 + q;
                f16x8 af = *(const f16x8*)&buf[sl * 512 + (((wr + l15) ^ (sl & 7)) << 3)];
                const _Float16* bks = bp + (size_t)(c * 4 + ks) * 4096;
                f16x8 bf[8];
#pragma unroll
                for (int j = 0; j < 8; j++) bf[j] = *(const f16x8*)(bks + j * 128);
#pragma unroll
                for (int j = 0; j < 8; j++)
                    acc[j] = __builtin_amdgcn_mfma_f32_16x16x32_f16(af, bf[j], acc[j], 0, 0, 0);
            }
        }
        if (more) {
            _Float16* __restrict__ buf = As[(c + 1) & 1];
#pragma unroll
            for (int i = 0; i < 4; i++) {
                int row = wr + r4 + i * 4;
                *(f16x8*)&buf[c16 * 512 + ((row ^ (c16 & 7)) << 3)] = st[i];
            }
        }
        __syncthreads();
    }

#pragma unroll
    for (int rg = 0; rg < 4; rg++) {
        int row = brow + wr + q * 4 + rg;
        if (row < M) {
#pragma unroll
            for (int j = 0; j < 8; j++) {
                float v = acc[j][rg] + bj[j];
                v = (v >= 0.f) ? v : 0.01f * v;
                C16[(size_t)row * ldc + j * 16 + l15] = (_Float16)v;
            }
        }
    }
}

// ---------------- raw-x gather (mean commutes with the relation GEMM) -------------
// MODE 0: m_r[dst] = mean x[src] -> M[N,256] (m0 cols 0..127, m1 cols 128..255).
// MODE 1: out[dst] = x[dst]@Wfin_x + sum_r m_r@Wfin_r + bfin (OUT==3).
// X tables are dense [N,128] now (12.8MB span; no writes churning read lines).
template<int MODE>
__global__ __launch_bounds__(256) void gather_k(const _Float16* __restrict__ X,
    int ldx, _Float16* __restrict__ Mout, const int* __restrict__ elist,
    const int* __restrict__ cnt, int N,
    const float* __restrict__ wfin, const float* __restrict__ bfin,
    float* __restrict__ out)
{
    int wv = blockIdx.x * 4 + (threadIdx.x >> 6);
    int l  = threadIdx.x & 63;
    if (wv >= N) return;

    const int eo   = l >> 4;
    const int e2   = eo & 1;
    const int half = l >> 5;              // 0: rel0, 1: rel1
    const int c8   = (l & 15) * 8;

    int dr = cnt[(size_t)half * N + wv];
    int d  = dr < CAP ? dr : CAP;
    float inv = dr > 0 ? 1.f / (float)dr : 0.f;
    const int* lst = elist + ((size_t)half * N + wv) * CAP;

    float acc[8];
#pragma unroll
    for (int j = 0; j < 8; j++) acc[j] = 0.f;

    const f16x8 zv = {};
    for (int p = e2; p < d; p += 8) {
        int p1 = p + 2, p2 = p + 4, p3 = p + 6;
        int s0 = lst[p];
        f16x8 v0 = *(const f16x8*)&X[(size_t)s0 * ldx + c8];
        f16x8 v1 = zv, v2 = zv, v3 = zv;
        if (p1 < d) { int s = lst[p1]; v1 = *(const f16x8*)&X[(size_t)s * ldx + c8]; }
        if (p2 < d) { int s = lst[p2]; v2 = *(const f16x8*)&X[(size_t)s * ldx + c8]; }
        if (p3 < d) { int s = lst[p3]; v3 = *(const f16x8*)&X[(size_t)s * ldx + c8]; }
#pragma unroll
        for (int j = 0; j < 8; j++)
            acc[j] += (float)v0[j] + (float)v1[j] + (float)v2[j] + (float)v3[j];
    }

    // merge the two slot copies within each half (convergent), apply mean scale
#pragma unroll
    for (int j = 0; j < 8; j++) {
        acc[j] += __shfl_xor(acc[j], 16);
        acc[j] *= inv;
    }

    if (MODE == 0) {
        if (eo == 0 || eo == 2) {
            f16x8 o;
#pragma unroll
            for (int j = 0; j < 8; j++) o[j] = (_Float16)acc[j];
            *(f16x8*)&Mout[(size_t)wv * 256 + half * 128 + c8] = o;
        }
    } else {
        // eo==1 -> x[dst] part, eo==0 -> rel0 part, eo==2 -> rel1 part, eo==3 idle
        float p0 = 0.f, p1 = 0.f, p2 = 0.f;
        if (eo == 1) {
            f16x8 xv = *(const f16x8*)&X[(size_t)wv * ldx + c8];
#pragma unroll
            for (int j = 0; j < 8; j++) {
                float xf = (float)xv[j];
                const float* wr = wfin + (size_t)(c8 + j) * 3;
                p0 += xf * wr[0]; p1 += xf * wr[1]; p2 += xf * wr[2];
            }
        } else if (eo == 0 || eo == 2) {
            const float* wb = wfin + (size_t)(eo == 0 ? 1 : 2) * H * 3;
#pragma unroll
            for (int j = 0; j < 8; j++) {
                const float* wr = wb + (size_t)(c8 + j) * 3;
                p0 += acc[j] * wr[0]; p1 += acc[j] * wr[1]; p2 += acc[j] * wr[2];
            }
        }
        // convergent full-wave reduction
#pragma unroll
        for (int off = 1; off <= 32; off <<= 1) {
            p0 += __shfl_xor(p0, off);
            p1 += __shfl_xor(p1, off);
            p2 += __shfl_xor(p2, off);
        }
        if (l == 0) {
            out[(size_t)wv * 3 + 0] = p0 + bfin[0];
            out[(size_t)wv * 3 + 1] = p1 + bfin[1];
            out[(size_t)wv * 3 + 2] = p2 + bfin[2];
        }
    }
}

// ---------------- concat GEMM: x2 = [x|m0|m1] @ Wcat + b_conv (K=384) -------------
// 512 thr = 8 waves x 16 cols, grid-stride 16-row tiles, B (12 frags) in regs,
// next tile's x/m frags prefetched. X from X1[N,128], M from M[N,256].
__global__ __launch_bounds__(512) void gemm_cat(const _Float16* __restrict__ X1,
    const _Float16* __restrict__ Mt, const _Float16* __restrict__ WT,
    const float* __restrict__ bias, _Float16* __restrict__ X2, int M, int mtiles)
{
    const int w   = threadIdx.x >> 6;
    const int l   = threadIdx.x & 63;
    const int l15 = l & 15;
    const int q   = l >> 4;
    const int col = w * 16 + l15;

    f16x8 bf[12];
    {
        const _Float16* wpp = WT + (size_t)col * 384 + q * 8;
#pragma unroll
        for (int c = 0; c < 12; c++) bf[c] = *(const f16x8*)(wpp + c * 32);
    }
    const float bj = bias[col];

    int t = blockIdx.x;
    if (t >= mtiles) return;
    f16x8 xf[12];
    {
        const _Float16* xp = X1 + ((size_t)t * 16 + l15) * 128 + q * 8;
        const _Float16* mp = Mt + ((size_t)t * 16 + l15) * 256 + q * 8;
#pragma unroll
        for (int c = 0; c < 4; c++) xf[c] = *(const f16x8*)(xp + c * 32);
#pragma unroll
        for (int c = 4; c < 12; c++) xf[c] = *(const f16x8*)(mp + (c - 4) * 32);
    }

    const f32x4 z4 = {0.f, 0.f, 0.f, 0.f};
    while (true) {
        int tn = t + gridDim.x;
        bool more = tn < mtiles;
        f16x8 xnf[12];
        if (more) {
            const _Float16* xp = X1 + ((size_t)tn * 16 + l15) * 128 + q * 8;
            const _Float16* mp = Mt + ((size_t)tn * 16 + l15) * 256 + q * 8;
#pragma unroll
            for (int c = 0; c < 4; c++) xnf[c] = *(const f16x8*)(xp + c * 32);
#pragma unroll
            for (int c = 4; c < 12; c++) xnf[c] = *(const f16x8*)(mp + (c - 4) * 32);
        }

        f32x4 a0 = z4;
#pragma unroll
        for (int c = 0; c < 12; c++)
            a0 = __builtin_amdgcn_mfma_f32_16x16x32_f16(xf[c], bf[c], a0, 0, 0, 0);

#pragma unroll
        for (int rg = 0; rg < 4; rg++) {
            int row = t * 16 + q * 4 + rg;
            if (row < M) X2[(size_t)row * 128 + col] = (_Float16)(a0[rg] + bj);
        }
        if (!more) break;
        t = tn;
#pragma unroll
        for (int c = 0; c < 12; c++) xf[c] = xnf[c];
    }
}

// ---------------- generic projection fallback (OUT != 3) -------------------------
__global__ __launch_bounds__(256) void proj_generic(const _Float16* __restrict__ X2,
    const _Float16* __restrict__ Mt, const float* __restrict__ wfin,
    const float* __restrict__ bfin, float* __restrict__ out, int N, int OUT)
{
    int row = blockIdx.x * 4 + (threadIdx.x >> 6);
    int l = threadIdx.x & 63;
    if (row >= N) return;
    float xv[6];
#pragma unroll
    for (int i = 0; i < 6; i++) {
        int k = l * 6 + i;
        xv[i] = (k < 128) ? (float)X2[(size_t)row * 128 + k]
                          : (float)Mt[(size_t)row * 256 + (k - 128)];
    }
    for (int c = 0; c < OUT; c++) {
        float p = 0.f;
#pragma unroll
        for (int i = 0; i < 6; i++) p += xv[i] * wfin[(size_t)(l * 6 + i) * OUT + c];
        for (int off = 32; off > 0; off >>= 1) p += __shfl_down(p, off);
        if (l == 0) out[(size_t)row * OUT + c] = p + bfin[c];
    }
}

extern "C" void kernel_launch(void* const* d_in, const int* in_sizes, int n_in,
                              void* d_out, int out_size, void* d_ws, size_t ws_size,
                              hipStream_t stream) {
    const float* feature = (const float*)d_in[0];
    const int*   ei      = (const int*)d_in[1];   // [2,E]: src then dst
    const int*   et      = (const int*)d_in[2];   // [E]
    const float* w_in    = (const float*)d_in[3];
    const float* b_in    = (const float*)d_in[4];
    const float* w_rel   = (const float*)d_in[5];
    const float* w_root  = (const float*)d_in[6];
    const float* b_conv  = (const float*)d_in[7];
    const float* w_out   = (const float*)d_in[8];
    const float* b_out   = (const float*)d_in[9];

    const int HH   = in_sizes[4];                 // 128
    const int D_IN = in_sizes[3] / HH;            // 768
    const int N    = in_sizes[0] / D_IN;          // 50000
    const int E    = in_sizes[1] / 2;              // 600000
    const int OUT  = in_sizes[9];                 // 3

    // workspace layout (16B-aligned segments)
    char* base = (char*)d_ws;
    _Float16* A16   = (_Float16*)base;                             // N*768
    _Float16* wInT  = A16 + (size_t)N * D_IN;                      // 768*128 packed
    _Float16* wcatT = wInT + (size_t)D_IN * HH;                    // 128*384
    _Float16* X1    = wcatT + (size_t)HH * 384;                    // N*128
    _Float16* X2    = X1 + (size_t)N * HH;                         // N*128
    _Float16* Mt    = X2 + (size_t)N * HH;                         // N*256
    float* wfin     = (float*)(Mt + (size_t)N * 256);              // 3*128*OUT
    float* bfin     = wfin + (size_t)3 * HH * (OUT > 0 ? OUT : 1); // OUT
    int* cnt        = (int*)(bfin + ((OUT + 3) & ~3));             // 2N
    int* elist      = cnt + (size_t)2 * N;                         // 2N*CAP

    hipMemsetAsync(cnt, 0, sizeof(int) * (size_t)2 * N, stream);
    prep_w<<<(D_IN * HH + HH * 384 + 255) / 256, 256, 0, stream>>>(
        w_in, w_root, w_rel, wInT, wcatT, D_IN);
    prep_fin<<<(3 * HH * OUT + OUT + 255) / 256, 256, 0, stream>>>(
        w_root, w_rel, b_conv, w_out, b_out, wfin, bfin, OUT);
    hist_fill<<<(E + 255) / 256, 256, 0, stream>>>(ei, ei + E, et, cnt, elist, E, N);

    // feature -> fp16 (streaming), then fp16-A GEMM
    long long total8 = (long long)N * D_IN / 8;
    cvt_feat<<<2048, 256, 0, stream>>>(feature, A16, total8);
    gemm_big<<<(N + 63) / 64, 256, 0, stream>>>(A16, wInT, b_in, X1, N, D_IN, HH);

    const int mtiles  = (N + 15) / 16;
    const int gblocks = (N + 3) / 4;

    // layer 1: gather raw x means, then one K=384 GEMM
    gather_k<0><<<gblocks, 256, 0, stream>>>(X1, 128, Mt, elist, cnt, N,
                                             nullptr, nullptr, nullptr);
    gemm_cat<<<1024, 512, 0, stream>>>(X1, Mt, wcatT, b_conv, X2, N, mtiles);
    if (OUT == 3) {
        // layer 2 + output projection fused into the gather
        gather_k<1><<<gblocks, 256, 0, stream>>>(X2, 128, nullptr, elist, cnt, N,
                                                 wfin, bfin, (float*)d_out);
    } else {
        gather_k<0><<<gblocks, 256, 0, stream>>>(X2, 128, Mt, elist, cnt, N,
                                                 nullptr, nullptr, nullptr);
        proj_generic<<<gblocks, 256, 0, stream>>>(X2, Mt, wfin, bfin,
                                                  (float*)d_out, N, OUT);
    }
}

// Round 9
// 440.062 us; speedup vs baseline: 1.0501x; 1.0501x over previous
//
#include <hip/hip_runtime.h>

#define H 128          // hidden dim (fixed by problem)
#define CAP 64         // max edges per (rel,dst) bucket

typedef _Float16 f16x8 __attribute__((ext_vector_type(8)));
typedef float    f32x4 __attribute__((ext_vector_type(4)));

// ---------------- edge bucketing: one pass, reused by both layers ----------------
__global__ __launch_bounds__(256) void hist_fill(const int* __restrict__ src,
    const int* __restrict__ dst, const int* __restrict__ et,
    int* __restrict__ cnt, int* __restrict__ elist, int E, int N)
{
    int e = blockIdx.x * 256 + threadIdx.x;
    if (e >= E) return;
    int s = src[e], d = dst[e], t = et[e];
    int b = t * N + d;
    int pos = atomicAdd(&cnt[b], 1);
    if (pos < CAP) elist[(size_t)b * CAP + pos] = s;
}

// ---------------- weight prep ----------------
// wInT: packed MFMA-B-fragment order for gemm_big (proven layout).
// wcatT: [col][384] f16 = concat_k(W_root;W_0;W_1) transposed — B for gemm_cat.
__global__ __launch_bounds__(256) void prep_w(const float* __restrict__ w_in,
    const float* __restrict__ w_root, const float* __restrict__ w_rel,
    _Float16* __restrict__ wInT, _Float16* __restrict__ wcatT, int K)
{
    int idx = blockIdx.x * 256 + threadIdx.x;
    int tot1 = K * H;                                  // 98304
    if (idx < tot1) {
        int k = idx >> 7, c = idx & 127;               // coalesced read of w_in
        int o = ((k >> 3) << 10) + (c << 3) + (k & 7); // ((k/8)*H + c)*8 + k%8
        wInT[o] = (_Float16)w_in[idx];
    } else {
        int i2 = idx - tot1;                           // < 128*384 = 49152
        if (i2 < H * 384) {
            int c = i2 / 384, k = i2 - c * 384;
            float v;
            if (k < 128)      v = w_root[(size_t)k * H + c];
            else if (k < 256) v = w_rel[(size_t)(k - 128) * H + c];
            else              v = w_rel[(size_t)H * H + (size_t)(k - 256) * H + c];
            wcatT[i2] = (_Float16)v;
        }
    }
}

// wfin[m][k][c] = W_m @ w_out ; bfin = b_conv@Wo + bo. One thread per output elem.
__global__ __launch_bounds__(256) void prep_fin(const float* __restrict__ w_root,
    const float* __restrict__ w_rel, const float* __restrict__ b_conv,
    const float* __restrict__ w_out, const float* __restrict__ b_out,
    float* __restrict__ wfin, float* __restrict__ bfin, int OUT)
{
    int idx = blockIdx.x * 256 + threadIdx.x;
    int nw = 3 * H * OUT;
    if (idx < nw) {
        int mk = idx / OUT, c = idx - mk * OUT;
        int m = mk >> 7, k = mk & 127;
        const float* W = (m == 0) ? w_root : (w_rel + (size_t)(m - 1) * H * H);
        float s = 0.f;
        for (int j = 0; j < H; j++)
            s += W[(size_t)k * H + j] * w_out[(size_t)j * OUT + c];
        wfin[(size_t)mk * OUT + c] = s;
    } else if (idx < nw + OUT) {
        int c = idx - nw;
        float s = b_out[c];
        for (int j = 0; j < H; j++) s += b_conv[j] * w_out[(size_t)j * OUT + c];
        bfin[c] = s;
    }
}

__device__ __forceinline__ f16x8 cvt8(float4 v0, float4 v1) {
    f16x8 t;
    t[0] = (_Float16)v0.x; t[1] = (_Float16)v0.y; t[2] = (_Float16)v0.z; t[3] = (_Float16)v0.w;
    t[4] = (_Float16)v1.x; t[5] = (_Float16)v1.y; t[6] = (_Float16)v1.z; t[7] = (_Float16)v1.w;
    return t;
}

// ---------------- big MFMA GEMM v6: global_load_lds direct staging ---------------
// X1 = fp16(leakyrelu(A[M,768] @ W + b)).
// r0-r7 post-mortem: five staging structures all ~71-103us; wall insensitive to
// LDS/regs, barriers, occupancy, run length, bytes, request count. Remaining
// structural delta vs the guide's proven m97 ladder: VGPR round-trip staging
// (Common-mistake #1). v6 = m97 pattern: fp32 A DMA'd straight to LDS via
// __builtin_amdgcn_global_load_lds width=16, wave-local 8KB regions, dbuf,
// one barrier per 128-k chunk. gll writes linearly (base+lane*16), so the
// bank-swizzle is applied BOTH at the global source addr (stage) and the
// ds_read addr (consume): phys_granule = logical ^ (row&7); LDS stays linear
// (m201's legal pattern). fp32->f16 cvt at read (8 VALU per 8 MFMA).
// [r8: container failed twice = infra-level error (same as r2, which passed on
//  identical resubmit). Audit: gll dest wave-uniform, size literal 16, bounds
//  ok, LDS 64KB x2 blocks ok. Resubmitting unchanged for clean attribution.]
__global__ __launch_bounds__(256, 2) void gemm_big(const float* __restrict__ A,
    const _Float16* __restrict__ WP, const float* __restrict__ bias,
    _Float16* __restrict__ C16, int M, int K, int ldc)
{
    __shared__ float As[2][4][2048];   // [buf][wave][16 rows x 128 cols fp32] = 64KB

    const int tid = threadIdx.x;
    const int w   = tid >> 6;
    const int l   = tid & 63;
    const int l15 = l & 15;
    const int q   = l >> 4;
    const int brow = blockIdx.x * 64;
    const int wr   = w * 16;

    const int lh  = l >> 5;            // row parity within a gll instr
    const int l31 = l & 31;            // physical 16B granule this lane fills

    // packed B: 32-k step s, frag j -> WP + s*4096 + (q*H + j*16 + l15)*8
    const _Float16* bp = WP + ((size_t)q * H + l15) * 8;

    float bj[8];
#pragma unroll
    for (int j = 0; j < 8; j++) bj[j] = bias[j * 16 + l15];

    f32x4 acc[8];
    const f32x4 z4 = {0.f, 0.f, 0.f, 0.f};
#pragma unroll
    for (int j = 0; j < 8; j++) acc[j] = z4;

    const int chunks = K / 128;        // 6

    // stage chunk c into buffer nbuf: 8 gll instrs, each covers 2 rows (1KB).
    // lane l -> LDS bytes [i*1024 + l*16): row = 2i+lh, phys granule p = l31;
    // source = logical granule p ^ (row&7) of that row (inverse swizzle).
#define STAGE(c, nbuf)                                                          \
    {                                                                           \
        _Pragma("unroll")                                                       \
        for (int i = 0; i < 8; i++) {                                           \
            int r  = 2 * i + lh;                                                \
            int gr = brow + wr + r; if (gr >= M) gr = M - 1;                    \
            int cg = l31 ^ (r & 7);                                             \
            const float* ga = A + (size_t)gr * K + (c) * 128 + cg * 4;          \
            __builtin_amdgcn_global_load_lds(                                   \
                (const __attribute__((address_space(1))) void*)ga,              \
                (__attribute__((address_space(3))) void*)&As[nbuf][w][i * 256], \
                16, 0, 0);                                                      \
        }                                                                       \
    }

    STAGE(0, 0);
    __syncthreads();                   // compiler drains vmcnt before barrier

    for (int c = 0; c < chunks; c++) {
        if (c + 1 < chunks) STAGE(c + 1, (c + 1) & 1);

        const float* wbuf = As[c & 1][w];
#pragma unroll
        for (int ks = 0; ks < 4; ks++) {
            const int sl = ks * 4 + q;
            const int xr = l15 & 7;
            const int p0 = (2 * sl) ^ xr;
            const int p1 = (2 * sl + 1) ^ xr;
            float4 lo = *(const float4*)&wbuf[l15 * 128 + p0 * 4];
            float4 hi = *(const float4*)&wbuf[l15 * 128 + p1 * 4];
            f16x8 af = cvt8(lo, hi);
            const _Float16* bks = bp + (size_t)(c * 4 + ks) * 4096;
            f16x8 bf[8];
#pragma unroll
            for (int j = 0; j < 8; j++) bf[j] = *(const f16x8*)(bks + j * 128);
#pragma unroll
            for (int j = 0; j < 8; j++)
                acc[j] = __builtin_amdgcn_mfma_f32_16x16x32_f16(af, bf[j], acc[j], 0, 0, 0);
        }
        __syncthreads();               // next-chunk DMA drained + buffers swap
    }
#undef STAGE

    // epilogue: bias + leaky, fp16 store (C frag: row = q*4+rg, col = j*16+l15)
#pragma unroll
    for (int rg = 0; rg < 4; rg++) {
        int row = brow + wr + q * 4 + rg;
        if (row < M) {
#pragma unroll
            for (int j = 0; j < 8; j++) {
                float v = acc[j][rg] + bj[j];
                v = (v >= 0.f) ? v : 0.01f * v;
                C16[(size_t)row * ldc + j * 16 + l15] = (_Float16)v;
            }
        }
    }
}

// ---------------- raw-x gather (mean commutes with the relation GEMM) -------------
// MODE 0: m_r[dst] = mean x[src] -> M[N,256]. MODE 1: fused final projection.
template<int MODE>
__global__ __launch_bounds__(256) void gather_k(const _Float16* __restrict__ X,
    int ldx, _Float16* __restrict__ Mout, const int* __restrict__ elist,
    const int* __restrict__ cnt, int N,
    const float* __restrict__ wfin, const float* __restrict__ bfin,
    float* __restrict__ out)
{
    int wv = blockIdx.x * 4 + (threadIdx.x >> 6);
    int l  = threadIdx.x & 63;
    if (wv >= N) return;

    const int eo   = l >> 4;
    const int e2   = eo & 1;
    const int half = l >> 5;              // 0: rel0, 1: rel1
    const int c8   = (l & 15) * 8;

    int dr = cnt[(size_t)half * N + wv];
    int d  = dr < CAP ? dr : CAP;
    float inv = dr > 0 ? 1.f / (float)dr : 0.f;
    const int* lst = elist + ((size_t)half * N + wv) * CAP;

    float acc[8];
#pragma unroll
    for (int j = 0; j < 8; j++) acc[j] = 0.f;

    const f16x8 zv = {};
    for (int p = e2; p < d; p += 8) {
        int p1 = p + 2, p2 = p + 4, p3 = p + 6;
        int s0 = lst[p];
        f16x8 v0 = *(const f16x8*)&X[(size_t)s0 * ldx + c8];
        f16x8 v1 = zv, v2 = zv, v3 = zv;
        if (p1 < d) { int s = lst[p1]; v1 = *(const f16x8*)&X[(size_t)s * ldx + c8]; }
        if (p2 < d) { int s = lst[p2]; v2 = *(const f16x8*)&X[(size_t)s * ldx + c8]; }
        if (p3 < d) { int s = lst[p3]; v3 = *(const f16x8*)&X[(size_t)s * ldx + c8]; }
#pragma unroll
        for (int j = 0; j < 8; j++)
            acc[j] += (float)v0[j] + (float)v1[j] + (float)v2[j] + (float)v3[j];
    }

    // merge the two slot copies within each half (convergent), apply mean scale
#pragma unroll
    for (int j = 0; j < 8; j++) {
        acc[j] += __shfl_xor(acc[j], 16);
        acc[j] *= inv;
    }

    if (MODE == 0) {
        if (eo == 0 || eo == 2) {
            f16x8 o;
#pragma unroll
            for (int j = 0; j < 8; j++) o[j] = (_Float16)acc[j];
            *(f16x8*)&Mout[(size_t)wv * 256 + half * 128 + c8] = o;
        }
    } else {
        // eo==1 -> x[dst] part, eo==0 -> rel0 part, eo==2 -> rel1 part, eo==3 idle
        float p0 = 0.f, p1 = 0.f, p2 = 0.f;
        if (eo == 1) {
            f16x8 xv = *(const f16x8*)&X[(size_t)wv * ldx + c8];
#pragma unroll
            for (int j = 0; j < 8; j++) {
                float xf = (float)xv[j];
                const float* wr = wfin + (size_t)(c8 + j) * 3;
                p0 += xf * wr[0]; p1 += xf * wr[1]; p2 += xf * wr[2];
            }
        } else if (eo == 0 || eo == 2) {
            const float* wb = wfin + (size_t)(eo == 0 ? 1 : 2) * H * 3;
#pragma unroll
            for (int j = 0; j < 8; j++) {
                const float* wr = wb + (size_t)(c8 + j) * 3;
                p0 += acc[j] * wr[0]; p1 += acc[j] * wr[1]; p2 += acc[j] * wr[2];
            }
        }
        // convergent full-wave reduction
#pragma unroll
        for (int off = 1; off <= 32; off <<= 1) {
            p0 += __shfl_xor(p0, off);
            p1 += __shfl_xor(p1, off);
            p2 += __shfl_xor(p2, off);
        }
        if (l == 0) {
            out[(size_t)wv * 3 + 0] = p0 + bfin[0];
            out[(size_t)wv * 3 + 1] = p1 + bfin[1];
            out[(size_t)wv * 3 + 2] = p2 + bfin[2];
        }
    }
}

// ---------------- concat GEMM: x2 = [x|m0|m1] @ Wcat + b_conv (K=384) -------------
__global__ __launch_bounds__(512) void gemm_cat(const _Float16* __restrict__ X1,
    const _Float16* __restrict__ Mt, const _Float16* __restrict__ WT,
    const float* __restrict__ bias, _Float16* __restrict__ X2, int M, int mtiles)
{
    const int w   = threadIdx.x >> 6;
    const int l   = threadIdx.x & 63;
    const int l15 = l & 15;
    const int q   = l >> 4;
    const int col = w * 16 + l15;

    f16x8 bf[12];
    {
        const _Float16* wpp = WT + (size_t)col * 384 + q * 8;
#pragma unroll
        for (int c = 0; c < 12; c++) bf[c] = *(const f16x8*)(wpp + c * 32);
    }
    const float bj = bias[col];

    int t = blockIdx.x;
    if (t >= mtiles) return;
    f16x8 xf[12];
    {
        const _Float16* xp = X1 + ((size_t)t * 16 + l15) * 128 + q * 8;
        const _Float16* mp = Mt + ((size_t)t * 16 + l15) * 256 + q * 8;
#pragma unroll
        for (int c = 0; c < 4; c++) xf[c] = *(const f16x8*)(xp + c * 32);
#pragma unroll
        for (int c = 4; c < 12; c++) xf[c] = *(const f16x8*)(mp + (c - 4) * 32);
    }

    const f32x4 z4 = {0.f, 0.f, 0.f, 0.f};
    while (true) {
        int tn = t + gridDim.x;
        bool more = tn < mtiles;
        f16x8 xnf[12];
        if (more) {
            const _Float16* xp = X1 + ((size_t)tn * 16 + l15) * 128 + q * 8;
            const _Float16* mp = Mt + ((size_t)tn * 16 + l15) * 256 + q * 8;
#pragma unroll
            for (int c = 0; c < 4; c++) xnf[c] = *(const f16x8*)(xp + c * 32);
#pragma unroll
            for (int c = 4; c < 12; c++) xnf[c] = *(const f16x8*)(mp + (c - 4) * 32);
        }

        f32x4 a0 = z4;
#pragma unroll
        for (int c = 0; c < 12; c++)
            a0 = __builtin_amdgcn_mfma_f32_16x16x32_f16(xf[c], bf[c], a0, 0, 0, 0);

#pragma unroll
        for (int rg = 0; rg < 4; rg++) {
            int row = t * 16 + q * 4 + rg;
            if (row < M) X2[(size_t)row * 128 + col] = (_Float16)(a0[rg] + bj);
        }
        if (!more) break;
        t = tn;
#pragma unroll
        for (int c = 0; c < 12; c++) xf[c] = xnf[c];
    }
}

// ---------------- generic projection fallback (OUT != 3) -------------------------
__global__ __launch_bounds__(256) void proj_generic(const _Float16* __restrict__ X2,
    const _Float16* __restrict__ Mt, const float* __restrict__ wfin,
    const float* __restrict__ bfin, float* __restrict__ out, int N, int OUT)
{
    int row = blockIdx.x * 4 + (threadIdx.x >> 6);
    int l = threadIdx.x & 63;
    if (row >= N) return;
    float xv[6];
#pragma unroll
    for (int i = 0; i < 6; i++) {
        int k = l * 6 + i;
        xv[i] = (k < 128) ? (float)X2[(size_t)row * 128 + k]
                          : (float)Mt[(size_t)row * 256 + (k - 128)];
    }
    for (int c = 0; c < OUT; c++) {
        float p = 0.f;
#pragma unroll
        for (int i = 0; i < 6; i++) p += xv[i] * wfin[(size_t)(l * 6 + i) * OUT + c];
        for (int off = 32; off > 0; off >>= 1) p += __shfl_down(p, off);
        if (l == 0) out[(size_t)row * OUT + c] = p + bfin[c];
    }
}

extern "C" void kernel_launch(void* const* d_in, const int* in_sizes, int n_in,
                              void* d_out, int out_size, void* d_ws, size_t ws_size,
                              hipStream_t stream) {
    const float* feature = (const float*)d_in[0];
    const int*   ei      = (const int*)d_in[1];   // [2,E]: src then dst
    const int*   et      = (const int*)d_in[2];   // [E]
    const float* w_in    = (const float*)d_in[3];
    const float* b_in    = (const float*)d_in[4];
    const float* w_rel   = (const float*)d_in[5];
    const float* w_root  = (const float*)d_in[6];
    const float* b_conv  = (const float*)d_in[7];
    const float* w_out   = (const float*)d_in[8];
    const float* b_out   = (const float*)d_in[9];

    const int HH   = in_sizes[4];                 // 128
    const int D_IN = in_sizes[3] / HH;            // 768
    const int N    = in_sizes[0] / D_IN;          // 50000
    const int E    = in_sizes[1] / 2;             // 600000
    const int OUT  = in_sizes[9];                 // 3

    // workspace layout (16B-aligned segments)
    char* base = (char*)d_ws;
    _Float16* wInT  = (_Float16*)base;                             // 768*128 packed
    _Float16* wcatT = wInT + (size_t)D_IN * HH;                    // 128*384
    _Float16* X1    = wcatT + (size_t)HH * 384;                    // N*128
    _Float16* X2    = X1 + (size_t)N * HH;                         // N*128
    _Float16* Mt    = X2 + (size_t)N * HH;                         // N*256
    float* wfin     = (float*)(Mt + (size_t)N * 256);              // 3*128*OUT
    float* bfin     = wfin + (size_t)3 * HH * (OUT > 0 ? OUT : 1); // OUT
    int* cnt        = (int*)(bfin + ((OUT + 3) & ~3));             // 2N
    int* elist      = cnt + (size_t)2 * N;                         // 2N*CAP

    hipMemsetAsync(cnt, 0, sizeof(int) * (size_t)2 * N, stream);
    prep_w<<<(D_IN * HH + HH * 384 + 255) / 256, 256, 0, stream>>>(
        w_in, w_root, w_rel, wInT, wcatT, D_IN);
    prep_fin<<<(3 * HH * OUT + OUT + 255) / 256, 256, 0, stream>>>(
        w_root, w_rel, b_conv, w_out, b_out, wfin, bfin, OUT);
    hist_fill<<<(E + 255) / 256, 256, 0, stream>>>(ei, ei + E, et, cnt, elist, E, N);

    // X1 = fp16(leakyrelu(feature @ w_in + b_in)) — global_load_lds staged GEMM
    gemm_big<<<(N + 63) / 64, 256, 0, stream>>>(feature, wInT, b_in, X1, N, D_IN, HH);

    const int mtiles  = (N + 15) / 16;
    const int gblocks = (N + 3) / 4;

    // layer 1: gather raw x means, then one K=384 GEMM
    gather_k<0><<<gblocks, 256, 0, stream>>>(X1, 128, Mt, elist, cnt, N,
                                             nullptr, nullptr, nullptr);
    gemm_cat<<<1024, 512, 0, stream>>>(X1, Mt, wcatT, b_conv, X2, N, mtiles);
    if (OUT == 3) {
        // layer 2 + output projection fused into the gather
        gather_k<1><<<gblocks, 256, 0, stream>>>(X2, 128, nullptr, elist, cnt, N,
                                                 wfin, bfin, (float*)d_out);
    } else {
        gather_k<0><<<gblocks, 256, 0, stream>>>(X2, 128, Mt, elist, cnt, N,
                                                 nullptr, nullptr, nullptr);
        proj_generic<<<gblocks, 256, 0, stream>>>(X2, Mt, wfin, bfin,
                                                  (float*)d_out, N, OUT);
    }
}

// Round 10
// 421.110 us; speedup vs baseline: 1.0974x; 1.0450x over previous
//
#include <hip/hip_runtime.h>

#define H 128          // hidden dim (fixed by problem)
#define CAP 64         // max edges per (rel,dst) bucket

typedef _Float16 f16x8 __attribute__((ext_vector_type(8)));
typedef float    f32x4 __attribute__((ext_vector_type(4)));

// ---------------- edge bucketing: one pass, reused by both layers ----------------
// elist write is a pure random 4B scatter into 25.6MB -> nontemporal store to
// skip the read-for-ownership line fetch (halves the write-path traffic).
__global__ __launch_bounds__(256) void hist_fill(const int* __restrict__ src,
    const int* __restrict__ dst, const int* __restrict__ et,
    int* __restrict__ cnt, int* __restrict__ elist, int E, int N)
{
    int e = blockIdx.x * 256 + threadIdx.x;
    if (e >= E) return;
    int s = src[e], d = dst[e], t = et[e];
    int b = t * N + d;
    int pos = atomicAdd(&cnt[b], 1);
    if (pos < CAP) __builtin_nontemporal_store(s, &elist[(size_t)b * CAP + pos]);
}

// ---------------- weight prep ----------------
__global__ __launch_bounds__(256) void prep_w(const float* __restrict__ w_in,
    const float* __restrict__ w_root, const float* __restrict__ w_rel,
    _Float16* __restrict__ wInT, _Float16* __restrict__ wcatT, int K)
{
    int idx = blockIdx.x * 256 + threadIdx.x;
    int tot1 = K * H;                                  // 98304
    if (idx < tot1) {
        int k = idx >> 7, c = idx & 127;               // coalesced read of w_in
        int o = ((k >> 3) << 10) + (c << 3) + (k & 7); // ((k/8)*H + c)*8 + k%8
        wInT[o] = (_Float16)w_in[idx];
    } else {
        int i2 = idx - tot1;                           // < 128*384 = 49152
        if (i2 < H * 384) {
            int c = i2 / 384, k = i2 - c * 384;
            float v;
            if (k < 128)      v = w_root[(size_t)k * H + c];
            else if (k < 256) v = w_rel[(size_t)(k - 128) * H + c];
            else              v = w_rel[(size_t)H * H + (size_t)(k - 256) * H + c];
            wcatT[i2] = (_Float16)v;
        }
    }
}

// wfin[m][k][c] = W_m @ w_out ; bfin = b_conv@Wo + bo. One thread per output elem.
__global__ __launch_bounds__(256) void prep_fin(const float* __restrict__ w_root,
    const float* __restrict__ w_rel, const float* __restrict__ b_conv,
    const float* __restrict__ w_out, const float* __restrict__ b_out,
    float* __restrict__ wfin, float* __restrict__ bfin, int OUT)
{
    int idx = blockIdx.x * 256 + threadIdx.x;
    int nw = 3 * H * OUT;
    if (idx < nw) {
        int mk = idx / OUT, c = idx - mk * OUT;
        int m = mk >> 7, k = mk & 127;
        const float* W = (m == 0) ? w_root : (w_rel + (size_t)(m - 1) * H * H);
        float s = 0.f;
        for (int j = 0; j < H; j++)
            s += W[(size_t)k * H + j] * w_out[(size_t)j * OUT + c];
        wfin[(size_t)mk * OUT + c] = s;
    } else if (idx < nw + OUT) {
        int c = idx - nw;
        float s = b_out[c];
        for (int j = 0; j < H; j++) s += b_conv[j] * w_out[(size_t)j * OUT + c];
        bfin[c] = s;
    }
}

__device__ __forceinline__ f16x8 cvt8(float4 v0, float4 v1) {
    f16x8 t;
    t[0] = (_Float16)v0.x; t[1] = (_Float16)v0.y; t[2] = (_Float16)v0.z; t[3] = (_Float16)v0.w;
    t[4] = (_Float16)v1.x; t[5] = (_Float16)v1.y; t[6] = (_Float16)v1.z; t[7] = (_Float16)v1.w;
    return t;
}

// ---------------- big MFMA GEMM v6 (r9-verified): global_load_lds staging --------
// ~86us; parked — even the m97-proven structure hits the A-read wall (r0-r9).
__global__ __launch_bounds__(256, 2) void gemm_big(const float* __restrict__ A,
    const _Float16* __restrict__ WP, const float* __restrict__ bias,
    _Float16* __restrict__ C16, int M, int K, int ldc)
{
    __shared__ float As[2][4][2048];   // [buf][wave][16 rows x 128 cols fp32] = 64KB

    const int tid = threadIdx.x;
    const int w   = tid >> 6;
    const int l   = tid & 63;
    const int l15 = l & 15;
    const int q   = l >> 4;
    const int brow = blockIdx.x * 64;
    const int wr   = w * 16;

    const int lh  = l >> 5;            // row parity within a gll instr
    const int l31 = l & 31;            // physical 16B granule this lane fills

    const _Float16* bp = WP + ((size_t)q * H + l15) * 8;

    float bj[8];
#pragma unroll
    for (int j = 0; j < 8; j++) bj[j] = bias[j * 16 + l15];

    f32x4 acc[8];
    const f32x4 z4 = {0.f, 0.f, 0.f, 0.f};
#pragma unroll
    for (int j = 0; j < 8; j++) acc[j] = z4;

    const int chunks = K / 128;        // 6

#define STAGE(c, nbuf)                                                          \
    {                                                                           \
        _Pragma("unroll")                                                       \
        for (int i = 0; i < 8; i++) {                                           \
            int r  = 2 * i + lh;                                                \
            int gr = brow + wr + r; if (gr >= M) gr = M - 1;                    \
            int cg = l31 ^ (r & 7);                                             \
            const float* ga = A + (size_t)gr * K + (c) * 128 + cg * 4;          \
            __builtin_amdgcn_global_load_lds(                                   \
                (const __attribute__((address_space(1))) void*)ga,              \
                (__attribute__((address_space(3))) void*)&As[nbuf][w][i * 256], \
                16, 0, 0);                                                      \
        }                                                                       \
    }

    STAGE(0, 0);
    __syncthreads();

    for (int c = 0; c < chunks; c++) {
        if (c + 1 < chunks) STAGE(c + 1, (c + 1) & 1);

        const float* wbuf = As[c & 1][w];
#pragma unroll
        for (int ks = 0; ks < 4; ks++) {
            const int sl = ks * 4 + q;
            const int xr = l15 & 7;
            const int p0 = (2 * sl) ^ xr;
            const int p1 = (2 * sl + 1) ^ xr;
            float4 lo = *(const float4*)&wbuf[l15 * 128 + p0 * 4];
            float4 hi = *(const float4*)&wbuf[l15 * 128 + p1 * 4];
            f16x8 af = cvt8(lo, hi);
            const _Float16* bks = bp + (size_t)(c * 4 + ks) * 4096;
            f16x8 bf[8];
#pragma unroll
            for (int j = 0; j < 8; j++) bf[j] = *(const f16x8*)(bks + j * 128);
#pragma unroll
            for (int j = 0; j < 8; j++)
                acc[j] = __builtin_amdgcn_mfma_f32_16x16x32_f16(af, bf[j], acc[j], 0, 0, 0);
        }
        __syncthreads();
    }
#undef STAGE

#pragma unroll
    for (int rg = 0; rg < 4; rg++) {
        int row = brow + wr + q * 4 + rg;
        if (row < M) {
#pragma unroll
            for (int j = 0; j < 8; j++) {
                float v = acc[j][rg] + bj[j];
                v = (v >= 0.f) ? v : 0.01f * v;
                C16[(size_t)row * ldc + j * 16 + l15] = (_Float16)v;
            }
        }
    }
}

// ---------------- fused layer-1: gather means -> LDS -> concat GEMM --------------
// One block per 16-row tile. Phase 1: wave w gathers rows tile*16 + w*4..+3
// (same per-row logic as gather_k: halves=relations, 2 slots, 4-deep unroll,
// convergent xor-16 merge) and writes means to LDS Ml[16][264] (264-f16 row
// stride -> uniform bank spread on the phase-2 b128 reads). Phase 2: 4 waves x
// 2 col-frags = 128 cols; A-frags: cols 0..127 from X1 (global, L1-hot), cols
// 128..383 from Ml. Deletes the 25.6MB Mt write + re-read + one launch.
__global__ __launch_bounds__(256) void fused_l1(const _Float16* __restrict__ X1,
    const _Float16* __restrict__ WT, const float* __restrict__ bias,
    const int* __restrict__ elist, const int* __restrict__ cnt,
    _Float16* __restrict__ X2, int N)
{
    __shared__ _Float16 Ml[16][264];

    const int w   = threadIdx.x >> 6;
    const int l   = threadIdx.x & 63;
    const int l15 = l & 15;
    const int q   = l >> 4;
    const int r0  = blockIdx.x * 16;

    const int eo   = l >> 4;
    const int e2   = eo & 1;
    const int half = l >> 5;              // 0: rel0, 1: rel1
    const int c8   = l15 * 8;

    // ---- phase 1: gather 4 rows per wave ----
    const f16x8 zv = {};
#pragma unroll
    for (int i = 0; i < 4; i++) {
        const int rl = w * 4 + i;
        const int r  = r0 + rl;           // wave-uniform
        float acc[8];
#pragma unroll
        for (int j = 0; j < 8; j++) acc[j] = 0.f;
        float inv = 0.f;
        if (r < N) {
            int dr = cnt[(size_t)half * N + r];
            int d  = dr < CAP ? dr : CAP;
            inv = dr > 0 ? 1.f / (float)dr : 0.f;
            const int* lst = elist + ((size_t)half * N + r) * CAP;
            for (int p = e2; p < d; p += 8) {
                int p1 = p + 2, p2 = p + 4, p3 = p + 6;
                int s0 = lst[p];
                f16x8 v0 = *(const f16x8*)&X1[(size_t)s0 * H + c8];
                f16x8 v1 = zv, v2 = zv, v3 = zv;
                if (p1 < d) { int s = lst[p1]; v1 = *(const f16x8*)&X1[(size_t)s * H + c8]; }
                if (p2 < d) { int s = lst[p2]; v2 = *(const f16x8*)&X1[(size_t)s * H + c8]; }
                if (p3 < d) { int s = lst[p3]; v3 = *(const f16x8*)&X1[(size_t)s * H + c8]; }
#pragma unroll
                for (int j = 0; j < 8; j++)
                    acc[j] += (float)v0[j] + (float)v1[j] + (float)v2[j] + (float)v3[j];
            }
        }
        // convergent merge across the 2 slots of each half
#pragma unroll
        for (int j = 0; j < 8; j++) {
            acc[j] += __shfl_xor(acc[j], 16);
            acc[j] *= inv;
        }
        if (r < N && (eo == 0 || eo == 2)) {
            f16x8 o;
#pragma unroll
            for (int j = 0; j < 8; j++) o[j] = (_Float16)acc[j];
            *(f16x8*)&Ml[rl][half * 128 + c8] = o;
        }
    }
    __syncthreads();

    // ---- phase 2: concat GEMM for this tile (4 waves x 2 col-frags) ----
    int gr = r0 + l15; if (gr >= N) gr = N - 1;
    f16x8 xf[12];
    {
        const _Float16* xp = X1 + (size_t)gr * H + q * 8;
#pragma unroll
        for (int c = 0; c < 4; c++) xf[c] = *(const f16x8*)(xp + c * 32);
#pragma unroll
        for (int c = 4; c < 12; c++) xf[c] = *(const f16x8*)&Ml[l15][(c - 4) * 32 + q * 8];
    }

    const f32x4 z4 = {0.f, 0.f, 0.f, 0.f};
#pragma unroll
    for (int cf = 0; cf < 2; cf++) {
        const int col = w * 32 + cf * 16 + l15;
        f16x8 bf[12];
        const _Float16* wpp = WT + (size_t)col * 384 + q * 8;
#pragma unroll
        for (int c = 0; c < 12; c++) bf[c] = *(const f16x8*)(wpp + c * 32);
        f32x4 a0 = z4;
#pragma unroll
        for (int c = 0; c < 12; c++)
            a0 = __builtin_amdgcn_mfma_f32_16x16x32_f16(xf[c], bf[c], a0, 0, 0, 0);
        const float bj = bias[col];
#pragma unroll
        for (int rg = 0; rg < 4; rg++) {
            int row = r0 + q * 4 + rg;
            if (row < N) X2[(size_t)row * H + col] = (_Float16)(a0[rg] + bj);
        }
    }
}

// ---------------- raw-x gather (MODE 0: means to Mt; MODE 1: fused projection) ----
template<int MODE>
__global__ __launch_bounds__(256) void gather_k(const _Float16* __restrict__ X,
    int ldx, _Float16* __restrict__ Mout, const int* __restrict__ elist,
    const int* __restrict__ cnt, int N,
    const float* __restrict__ wfin, const float* __restrict__ bfin,
    float* __restrict__ out)
{
    int wv = blockIdx.x * 4 + (threadIdx.x >> 6);
    int l  = threadIdx.x & 63;
    if (wv >= N) return;

    const int eo   = l >> 4;
    const int e2   = eo & 1;
    const int half = l >> 5;              // 0: rel0, 1: rel1
    const int c8   = (l & 15) * 8;

    int dr = cnt[(size_t)half * N + wv];
    int d  = dr < CAP ? dr : CAP;
    float inv = dr > 0 ? 1.f / (float)dr : 0.f;
    const int* lst = elist + ((size_t)half * N + wv) * CAP;

    float acc[8];
#pragma unroll
    for (int j = 0; j < 8; j++) acc[j] = 0.f;

    const f16x8 zv = {};
    for (int p = e2; p < d; p += 8) {
        int p1 = p + 2, p2 = p + 4, p3 = p + 6;
        int s0 = lst[p];
        f16x8 v0 = *(const f16x8*)&X[(size_t)s0 * ldx + c8];
        f16x8 v1 = zv, v2 = zv, v3 = zv;
        if (p1 < d) { int s = lst[p1]; v1 = *(const f16x8*)&X[(size_t)s * ldx + c8]; }
        if (p2 < d) { int s = lst[p2]; v2 = *(const f16x8*)&X[(size_t)s * ldx + c8]; }
        if (p3 < d) { int s = lst[p3]; v3 = *(const f16x8*)&X[(size_t)s * ldx + c8]; }
#pragma unroll
        for (int j = 0; j < 8; j++)
            acc[j] += (float)v0[j] + (float)v1[j] + (float)v2[j] + (float)v3[j];
    }

#pragma unroll
    for (int j = 0; j < 8; j++) {
        acc[j] += __shfl_xor(acc[j], 16);
        acc[j] *= inv;
    }

    if (MODE == 0) {
        if (eo == 0 || eo == 2) {
            f16x8 o;
#pragma unroll
            for (int j = 0; j < 8; j++) o[j] = (_Float16)acc[j];
            *(f16x8*)&Mout[(size_t)wv * 256 + half * 128 + c8] = o;
        }
    } else {
        float p0 = 0.f, p1 = 0.f, p2 = 0.f;
        if (eo == 1) {
            f16x8 xv = *(const f16x8*)&X[(size_t)wv * ldx + c8];
#pragma unroll
            for (int j = 0; j < 8; j++) {
                float xf = (float)xv[j];
                const float* wr = wfin + (size_t)(c8 + j) * 3;
                p0 += xf * wr[0]; p1 += xf * wr[1]; p2 += xf * wr[2];
            }
        } else if (eo == 0 || eo == 2) {
            const float* wb = wfin + (size_t)(eo == 0 ? 1 : 2) * H * 3;
#pragma unroll
            for (int j = 0; j < 8; j++) {
                const float* wr = wb + (size_t)(c8 + j) * 3;
                p0 += acc[j] * wr[0]; p1 += acc[j] * wr[1]; p2 += acc[j] * wr[2];
            }
        }
#pragma unroll
        for (int off = 1; off <= 32; off <<= 1) {
            p0 += __shfl_xor(p0, off);
            p1 += __shfl_xor(p1, off);
            p2 += __shfl_xor(p2, off);
        }
        if (l == 0) {
            out[(size_t)wv * 3 + 0] = p0 + bfin[0];
            out[(size_t)wv * 3 + 1] = p1 + bfin[1];
            out[(size_t)wv * 3 + 2] = p2 + bfin[2];
        }
    }
}

// ---------------- concat GEMM (fallback path, OUT != 3) --------------------------
__global__ __launch_bounds__(512) void gemm_cat(const _Float16* __restrict__ X1,
    const _Float16* __restrict__ Mt, const _Float16* __restrict__ WT,
    const float* __restrict__ bias, _Float16* __restrict__ X2, int M, int mtiles)
{
    const int w   = threadIdx.x >> 6;
    const int l   = threadIdx.x & 63;
    const int l15 = l & 15;
    const int q   = l >> 4;
    const int col = w * 16 + l15;

    f16x8 bf[12];
    {
        const _Float16* wpp = WT + (size_t)col * 384 + q * 8;
#pragma unroll
        for (int c = 0; c < 12; c++) bf[c] = *(const f16x8*)(wpp + c * 32);
    }
    const float bj = bias[col];

    int t = blockIdx.x;
    if (t >= mtiles) return;
    f16x8 xf[12];
    {
        const _Float16* xp = X1 + ((size_t)t * 16 + l15) * 128 + q * 8;
        const _Float16* mp = Mt + ((size_t)t * 16 + l15) * 256 + q * 8;
#pragma unroll
        for (int c = 0; c < 4; c++) xf[c] = *(const f16x8*)(xp + c * 32);
#pragma unroll
        for (int c = 4; c < 12; c++) xf[c] = *(const f16x8*)(mp + (c - 4) * 32);
    }

    const f32x4 z4 = {0.f, 0.f, 0.f, 0.f};
    while (true) {
        int tn = t + gridDim.x;
        bool more = tn < mtiles;
        f16x8 xnf[12];
        if (more) {
            const _Float16* xp = X1 + ((size_t)tn * 16 + l15) * 128 + q * 8;
            const _Float16* mp = Mt + ((size_t)tn * 16 + l15) * 256 + q * 8;
#pragma unroll
            for (int c = 0; c < 4; c++) xnf[c] = *(const f16x8*)(xp + c * 32);
#pragma unroll
            for (int c = 4; c < 12; c++) xnf[c] = *(const f16x8*)(mp + (c - 4) * 32);
        }

        f32x4 a0 = z4;
#pragma unroll
        for (int c = 0; c < 12; c++)
            a0 = __builtin_amdgcn_mfma_f32_16x16x32_f16(xf[c], bf[c], a0, 0, 0, 0);

#pragma unroll
        for (int rg = 0; rg < 4; rg++) {
            int row = t * 16 + q * 4 + rg;
            if (row < M) X2[(size_t)row * 128 + col] = (_Float16)(a0[rg] + bj);
        }
        if (!more) break;
        t = tn;
#pragma unroll
        for (int c = 0; c < 12; c++) xf[c] = xnf[c];
    }
}

// ---------------- generic projection fallback (OUT != 3) -------------------------
__global__ __launch_bounds__(256) void proj_generic(const _Float16* __restrict__ X2,
    const _Float16* __restrict__ Mt, const float* __restrict__ wfin,
    const float* __restrict__ bfin, float* __restrict__ out, int N, int OUT)
{
    int row = blockIdx.x * 4 + (threadIdx.x >> 6);
    int l = threadIdx.x & 63;
    if (row >= N) return;
    float xv[6];
#pragma unroll
    for (int i = 0; i < 6; i++) {
        int k = l * 6 + i;
        xv[i] = (k < 128) ? (float)X2[(size_t)row * 128 + k]
                          : (float)Mt[(size_t)row * 256 + (k - 128)];
    }
    for (int c = 0; c < OUT; c++) {
        float p = 0.f;
#pragma unroll
        for (int i = 0; i < 6; i++) p += xv[i] * wfin[(size_t)(l * 6 + i) * OUT + c];
        for (int off = 32; off > 0; off >>= 1) p += __shfl_down(p, off);
        if (l == 0) out[(size_t)row * OUT + c] = p + bfin[c];
    }
}

extern "C" void kernel_launch(void* const* d_in, const int* in_sizes, int n_in,
                              void* d_out, int out_size, void* d_ws, size_t ws_size,
                              hipStream_t stream) {
    const float* feature = (const float*)d_in[0];
    const int*   ei      = (const int*)d_in[1];   // [2,E]: src then dst
    const int*   et      = (const int*)d_in[2];   // [E]
    const float* w_in    = (const float*)d_in[3];
    const float* b_in    = (const float*)d_in[4];
    const float* w_rel   = (const float*)d_in[5];
    const float* w_root  = (const float*)d_in[6];
    const float* b_conv  = (const float*)d_in[7];
    const float* w_out   = (const float*)d_in[8];
    const float* b_out   = (const float*)d_in[9];

    const int HH   = in_sizes[4];                 // 128
    const int D_IN = in_sizes[3] / HH;            // 768
    const int N    = in_sizes[0] / D_IN;          // 50000
    const int E    = in_sizes[1] / 2;             // 600000
    const int OUT  = in_sizes[9];                 // 3

    // workspace layout (16B-aligned segments)
    char* base = (char*)d_ws;
    _Float16* wInT  = (_Float16*)base;                             // 768*128 packed
    _Float16* wcatT = wInT + (size_t)D_IN * HH;                    // 128*384
    _Float16* X1    = wcatT + (size_t)HH * 384;                    // N*128
    _Float16* X2    = X1 + (size_t)N * HH;                         // N*128
    _Float16* Mt    = X2 + (size_t)N * HH;                         // N*256 (fallback only)
    float* wfin     = (float*)(Mt + (size_t)N * 256);              // 3*128*OUT
    float* bfin     = wfin + (size_t)3 * HH * (OUT > 0 ? OUT : 1); // OUT
    int* cnt        = (int*)(bfin + ((OUT + 3) & ~3));             // 2N
    int* elist      = cnt + (size_t)2 * N;                         // 2N*CAP

    hipMemsetAsync(cnt, 0, sizeof(int) * (size_t)2 * N, stream);
    prep_w<<<(D_IN * HH + HH * 384 + 255) / 256, 256, 0, stream>>>(
        w_in, w_root, w_rel, wInT, wcatT, D_IN);
    prep_fin<<<(3 * HH * OUT + OUT + 255) / 256, 256, 0, stream>>>(
        w_root, w_rel, b_conv, w_out, b_out, wfin, bfin, OUT);
    hist_fill<<<(E + 255) / 256, 256, 0, stream>>>(ei, ei + E, et, cnt, elist, E, N);

    // X1 = fp16(leakyrelu(feature @ w_in + b_in)) — global_load_lds staged GEMM
    gemm_big<<<(N + 63) / 64, 256, 0, stream>>>(feature, wInT, b_in, X1, N, D_IN, HH);

    const int mtiles  = (N + 15) / 16;
    const int gblocks = (N + 3) / 4;

    if (OUT == 3) {
        // layer 1: fused gather+concat-GEMM; layer 2: fused gather+projection
        fused_l1<<<mtiles, 256, 0, stream>>>(X1, wcatT, b_conv, elist, cnt, X2, N);
        gather_k<1><<<gblocks, 256, 0, stream>>>(X2, 128, nullptr, elist, cnt, N,
                                                 wfin, bfin, (float*)d_out);
    } else {
        gather_k<0><<<gblocks, 256, 0, stream>>>(X1, 128, Mt, elist, cnt, N,
                                                 nullptr, nullptr, nullptr);
        gemm_cat<<<1024, 512, 0, stream>>>(X1, Mt, wcatT, b_conv, X2, N, mtiles);
        gather_k<0><<<gblocks, 256, 0, stream>>>(X2, 128, Mt, elist, cnt, N,
                                                 nullptr, nullptr, nullptr);
        proj_generic<<<gblocks, 256, 0, stream>>>(X2, Mt, wfin, bfin,
                                                  (float*)d_out, N, OUT);
    }
}

// Round 11
// 398.699 us; speedup vs baseline: 1.1591x; 1.0562x over previous
//
#include <hip/hip_runtime.h>

#define H 128          // hidden dim (fixed by problem)
#define CAP 64         // max edges per (rel,dst) bucket

typedef _Float16 f16x8 __attribute__((ext_vector_type(8)));
typedef float    f32x4 __attribute__((ext_vector_type(4)));

// ---------------- unified weight prep (one launch) --------------------------------
// range 0: wInT packed MFMA-B-fragment order (gemm_big B, proven layout)
// range 1: wcatT [col][384] = concat_k(W_root;W_0;W_1)^T (gemm_cat/fused_l1 B)
// range 2: wfin[m][k][c] = W_m @ w_out (folded layer-2+projection)
// range 3: bfin = b_conv @ w_out + b_out
__global__ __launch_bounds__(256) void prep_all(const float* __restrict__ w_in,
    const float* __restrict__ w_root, const float* __restrict__ w_rel,
    const float* __restrict__ b_conv, const float* __restrict__ w_out,
    const float* __restrict__ b_out, _Float16* __restrict__ wInT,
    _Float16* __restrict__ wcatT, float* __restrict__ wfin,
    float* __restrict__ bfin, int K, int OUT)
{
    int idx = blockIdx.x * 256 + threadIdx.x;
    int tot1 = K * H;                                  // 98304
    if (idx < tot1) {
        int k = idx >> 7, c = idx & 127;               // coalesced read of w_in
        int o = ((k >> 3) << 10) + (c << 3) + (k & 7); // ((k/8)*H + c)*8 + k%8
        wInT[o] = (_Float16)w_in[idx];
        return;
    }
    int i2 = idx - tot1;
    if (i2 < H * 384) {
        int c = i2 / 384, k = i2 - c * 384;
        float v;
        if (k < 128)      v = w_root[(size_t)k * H + c];
        else if (k < 256) v = w_rel[(size_t)(k - 128) * H + c];
        else              v = w_rel[(size_t)H * H + (size_t)(k - 256) * H + c];
        wcatT[i2] = (_Float16)v;
        return;
    }
    int i3 = i2 - H * 384;
    int nw = 3 * H * OUT;
    if (i3 < nw) {
        int mk = i3 / OUT, c = i3 - mk * OUT;
        int m = mk >> 7, k = mk & 127;
        const float* W = (m == 0) ? w_root : (w_rel + (size_t)(m - 1) * H * H);
        float s = 0.f;
        for (int j = 0; j < H; j++)
            s += W[(size_t)k * H + j] * w_out[(size_t)j * OUT + c];
        wfin[(size_t)mk * OUT + c] = s;
    } else if (i3 < nw + OUT) {
        int c = i3 - nw;
        float s = b_out[c];
        for (int j = 0; j < H; j++) s += b_conv[j] * w_out[(size_t)j * OUT + c];
        bfin[c] = s;
    }
}

__device__ __forceinline__ f16x8 cvt8(float4 v0, float4 v1) {
    f16x8 t;
    t[0] = (_Float16)v0.x; t[1] = (_Float16)v0.y; t[2] = (_Float16)v0.z; t[3] = (_Float16)v0.w;
    t[4] = (_Float16)v1.x; t[5] = (_Float16)v1.y; t[6] = (_Float16)v1.z; t[7] = (_Float16)v1.w;
    return t;
}

// ---------------- combined: big MFMA GEMM (r9-verified v6) + edge bucketing ------
// blockIdx < gemmBlocks : one 64-row GEMM tile (global_load_lds staged, ~86us,
//   runs at only ~1 TB/s of 6.3 — huge idle memory slack).
// blockIdx >= gemmBlocks: one 256-edge hist block (random atomics + NT scatter,
//   data-independent of the GEMM) — overlapped under that slack instead of
//   serializing ~20-30us on the stream. memset(cnt) + prep_all precede on the
//   stream; gemm blocks dispatch first (lower blockIdx) so the long pole starts
//   immediately.
__global__ __launch_bounds__(256, 2) void gemm_hist(const float* __restrict__ A,
    const _Float16* __restrict__ WP, const float* __restrict__ bias,
    _Float16* __restrict__ C16, int M, int K, int ldc, int gemmBlocks,
    const int* __restrict__ esrc, const int* __restrict__ edst,
    const int* __restrict__ et, int* __restrict__ cnt, int* __restrict__ elist,
    int E, int N)
{
    __shared__ float As[2][4][2048];   // [buf][wave][16 rows x 128 cols fp32] = 64KB

    if ((int)blockIdx.x >= gemmBlocks) {
        // ---- edge-bucketing block ----
        int e = (blockIdx.x - gemmBlocks) * 256 + threadIdx.x;
        if (e < E) {
            int s = esrc[e], d = edst[e], t = et[e];
            int b = t * N + d;
            int pos = atomicAdd(&cnt[b], 1);
            if (pos < CAP)
                __builtin_nontemporal_store(s, &elist[(size_t)b * CAP + pos]);
        }
        return;
    }

    // ---- GEMM tile ----
    const int tid = threadIdx.x;
    const int w   = tid >> 6;
    const int l   = tid & 63;
    const int l15 = l & 15;
    const int q   = l >> 4;
    const int brow = blockIdx.x * 64;
    const int wr   = w * 16;

    const int lh  = l >> 5;            // row parity within a gll instr
    const int l31 = l & 31;            // physical 16B granule this lane fills

    const _Float16* bp = WP + ((size_t)q * H + l15) * 8;

    float bj[8];
#pragma unroll
    for (int j = 0; j < 8; j++) bj[j] = bias[j * 16 + l15];

    f32x4 acc[8];
    const f32x4 z4 = {0.f, 0.f, 0.f, 0.f};
#pragma unroll
    for (int j = 0; j < 8; j++) acc[j] = z4;

    const int chunks = K / 128;        // 6

#define STAGE(c, nbuf)                                                          \
    {                                                                           \
        _Pragma("unroll")                                                       \
        for (int i = 0; i < 8; i++) {                                           \
            int r  = 2 * i + lh;                                                \
            int gr = brow + wr + r; if (gr >= M) gr = M - 1;                    \
            int cg = l31 ^ (r & 7);                                             \
            const float* ga = A + (size_t)gr * K + (c) * 128 + cg * 4;          \
            __builtin_amdgcn_global_load_lds(                                   \
                (const __attribute__((address_space(1))) void*)ga,              \
                (__attribute__((address_space(3))) void*)&As[nbuf][w][i * 256], \
                16, 0, 0);                                                      \
        }                                                                       \
    }

    STAGE(0, 0);
    __syncthreads();

    for (int c = 0; c < chunks; c++) {
        if (c + 1 < chunks) STAGE(c + 1, (c + 1) & 1);

        const float* wbuf = As[c & 1][w];
#pragma unroll
        for (int ks = 0; ks < 4; ks++) {
            const int sl = ks * 4 + q;
            const int xr = l15 & 7;
            const int p0 = (2 * sl) ^ xr;
            const int p1 = (2 * sl + 1) ^ xr;
            float4 lo = *(const float4*)&wbuf[l15 * 128 + p0 * 4];
            float4 hi = *(const float4*)&wbuf[l15 * 128 + p1 * 4];
            f16x8 af = cvt8(lo, hi);
            const _Float16* bks = bp + (size_t)(c * 4 + ks) * 4096;
            f16x8 bf[8];
#pragma unroll
            for (int j = 0; j < 8; j++) bf[j] = *(const f16x8*)(bks + j * 128);
#pragma unroll
            for (int j = 0; j < 8; j++)
                acc[j] = __builtin_amdgcn_mfma_f32_16x16x32_f16(af, bf[j], acc[j], 0, 0, 0);
        }
        __syncthreads();
    }
#undef STAGE

#pragma unroll
    for (int rg = 0; rg < 4; rg++) {
        int row = brow + wr + q * 4 + rg;
        if (row < M) {
#pragma unroll
            for (int j = 0; j < 8; j++) {
                float v = acc[j][rg] + bj[j];
                v = (v >= 0.f) ? v : 0.01f * v;
                C16[(size_t)row * ldc + j * 16 + l15] = (_Float16)v;
            }
        }
    }
}

// ---------------- fused layer-1: gather means -> LDS -> concat GEMM --------------
// One block per 16-row tile. Phase 1: wave w gathers rows tile*16 + w*4..+3
// (halves=relations, 2 slots, 4-deep unroll, convergent xor-16 merge), means to
// LDS Ml[16][264]. Phase 2: concat GEMM for the tile (4 waves x 2 col-frags).
__global__ __launch_bounds__(256) void fused_l1(const _Float16* __restrict__ X1,
    const _Float16* __restrict__ WT, const float* __restrict__ bias,
    const int* __restrict__ elist, const int* __restrict__ cnt,
    _Float16* __restrict__ X2, int N)
{
    __shared__ _Float16 Ml[16][264];

    const int w   = threadIdx.x >> 6;
    const int l   = threadIdx.x & 63;
    const int l15 = l & 15;
    const int q   = l >> 4;
    const int r0  = blockIdx.x * 16;

    const int eo   = l >> 4;
    const int e2   = eo & 1;
    const int half = l >> 5;              // 0: rel0, 1: rel1
    const int c8   = l15 * 8;

    // ---- phase 1: gather 4 rows per wave ----
    const f16x8 zv = {};
#pragma unroll
    for (int i = 0; i < 4; i++) {
        const int rl = w * 4 + i;
        const int r  = r0 + rl;           // wave-uniform
        float acc[8];
#pragma unroll
        for (int j = 0; j < 8; j++) acc[j] = 0.f;
        float inv = 0.f;
        if (r < N) {
            int dr = cnt[(size_t)half * N + r];
            int d  = dr < CAP ? dr : CAP;
            inv = dr > 0 ? 1.f / (float)dr : 0.f;
            const int* lst = elist + ((size_t)half * N + r) * CAP;
            for (int p = e2; p < d; p += 8) {
                int p1 = p + 2, p2 = p + 4, p3 = p + 6;
                int s0 = lst[p];
                f16x8 v0 = *(const f16x8*)&X1[(size_t)s0 * H + c8];
                f16x8 v1 = zv, v2 = zv, v3 = zv;
                if (p1 < d) { int s = lst[p1]; v1 = *(const f16x8*)&X1[(size_t)s * H + c8]; }
                if (p2 < d) { int s = lst[p2]; v2 = *(const f16x8*)&X1[(size_t)s * H + c8]; }
                if (p3 < d) { int s = lst[p3]; v3 = *(const f16x8*)&X1[(size_t)s * H + c8]; }
#pragma unroll
                for (int j = 0; j < 8; j++)
                    acc[j] += (float)v0[j] + (float)v1[j] + (float)v2[j] + (float)v3[j];
            }
        }
        // convergent merge across the 2 slots of each half
#pragma unroll
        for (int j = 0; j < 8; j++) {
            acc[j] += __shfl_xor(acc[j], 16);
            acc[j] *= inv;
        }
        if (r < N && (eo == 0 || eo == 2)) {
            f16x8 o;
#pragma unroll
            for (int j = 0; j < 8; j++) o[j] = (_Float16)acc[j];
            *(f16x8*)&Ml[rl][half * 128 + c8] = o;
        }
    }
    __syncthreads();

    // ---- phase 2: concat GEMM for this tile (4 waves x 2 col-frags) ----
    int gr = r0 + l15; if (gr >= N) gr = N - 1;
    f16x8 xf[12];
    {
        const _Float16* xp = X1 + (size_t)gr * H + q * 8;
#pragma unroll
        for (int c = 0; c < 4; c++) xf[c] = *(const f16x8*)(xp + c * 32);
#pragma unroll
        for (int c = 4; c < 12; c++) xf[c] = *(const f16x8*)&Ml[l15][(c - 4) * 32 + q * 8];
    }

    const f32x4 z4 = {0.f, 0.f, 0.f, 0.f};
#pragma unroll
    for (int cf = 0; cf < 2; cf++) {
        const int col = w * 32 + cf * 16 + l15;
        f16x8 bf[12];
        const _Float16* wpp = WT + (size_t)col * 384 + q * 8;
#pragma unroll
        for (int c = 0; c < 12; c++) bf[c] = *(const f16x8*)(wpp + c * 32);
        f32x4 a0 = z4;
#pragma unroll
        for (int c = 0; c < 12; c++)
            a0 = __builtin_amdgcn_mfma_f32_16x16x32_f16(xf[c], bf[c], a0, 0, 0, 0);
        const float bj = bias[col];
#pragma unroll
        for (int rg = 0; rg < 4; rg++) {
            int row = r0 + q * 4 + rg;
            if (row < N) X2[(size_t)row * H + col] = (_Float16)(a0[rg] + bj);
        }
    }
}

// ---------------- raw-x gather (MODE 0: means to Mt; MODE 1: fused projection) ----
template<int MODE>
__global__ __launch_bounds__(256) void gather_k(const _Float16* __restrict__ X,
    int ldx, _Float16* __restrict__ Mout, const int* __restrict__ elist,
    const int* __restrict__ cnt, int N,
    const float* __restrict__ wfin, const float* __restrict__ bfin,
    float* __restrict__ out)
{
    int wv = blockIdx.x * 4 + (threadIdx.x >> 6);
    int l  = threadIdx.x & 63;
    if (wv >= N) return;

    const int eo   = l >> 4;
    const int e2   = eo & 1;
    const int half = l >> 5;              // 0: rel0, 1: rel1
    const int c8   = (l & 15) * 8;

    int dr = cnt[(size_t)half * N + wv];
    int d  = dr < CAP ? dr : CAP;
    float inv = dr > 0 ? 1.f / (float)dr : 0.f;
    const int* lst = elist + ((size_t)half * N + wv) * CAP;

    float acc[8];
#pragma unroll
    for (int j = 0; j < 8; j++) acc[j] = 0.f;

    const f16x8 zv = {};
    for (int p = e2; p < d; p += 8) {
        int p1 = p + 2, p2 = p + 4, p3 = p + 6;
        int s0 = lst[p];
        f16x8 v0 = *(const f16x8*)&X[(size_t)s0 * ldx + c8];
        f16x8 v1 = zv, v2 = zv, v3 = zv;
        if (p1 < d) { int s = lst[p1]; v1 = *(const f16x8*)&X[(size_t)s * ldx + c8]; }
        if (p2 < d) { int s = lst[p2]; v2 = *(const f16x8*)&X[(size_t)s * ldx + c8]; }
        if (p3 < d) { int s = lst[p3]; v3 = *(const f16x8*)&X[(size_t)s * ldx + c8]; }
#pragma unroll
        for (int j = 0; j < 8; j++)
            acc[j] += (float)v0[j] + (float)v1[j] + (float)v2[j] + (float)v3[j];
    }

#pragma unroll
    for (int j = 0; j < 8; j++) {
        acc[j] += __shfl_xor(acc[j], 16);
        acc[j] *= inv;
    }

    if (MODE == 0) {
        if (eo == 0 || eo == 2) {
            f16x8 o;
#pragma unroll
            for (int j = 0; j < 8; j++) o[j] = (_Float16)acc[j];
            *(f16x8*)&Mout[(size_t)wv * 256 + half * 128 + c8] = o;
        }
    } else {
        float p0 = 0.f, p1 = 0.f, p2 = 0.f;
        if (eo == 1) {
            f16x8 xv = *(const f16x8*)&X[(size_t)wv * ldx + c8];
#pragma unroll
            for (int j = 0; j < 8; j++) {
                float xf = (float)xv[j];
                const float* wr = wfin + (size_t)(c8 + j) * 3;
                p0 += xf * wr[0]; p1 += xf * wr[1]; p2 += xf * wr[2];
            }
        } else if (eo == 0 || eo == 2) {
            const float* wb = wfin + (size_t)(eo == 0 ? 1 : 2) * H * 3;
#pragma unroll
            for (int j = 0; j < 8; j++) {
                const float* wr = wb + (size_t)(c8 + j) * 3;
                p0 += acc[j] * wr[0]; p1 += acc[j] * wr[1]; p2 += acc[j] * wr[2];
            }
        }
#pragma unroll
        for (int off = 1; off <= 32; off <<= 1) {
            p0 += __shfl_xor(p0, off);
            p1 += __shfl_xor(p1, off);
            p2 += __shfl_xor(p2, off);
        }
        if (l == 0) {
            out[(size_t)wv * 3 + 0] = p0 + bfin[0];
            out[(size_t)wv * 3 + 1] = p1 + bfin[1];
            out[(size_t)wv * 3 + 2] = p2 + bfin[2];
        }
    }
}

// ---------------- concat GEMM (fallback path, OUT != 3) --------------------------
__global__ __launch_bounds__(512) void gemm_cat(const _Float16* __restrict__ X1,
    const _Float16* __restrict__ Mt, const _Float16* __restrict__ WT,
    const float* __restrict__ bias, _Float16* __restrict__ X2, int M, int mtiles)
{
    const int w   = threadIdx.x >> 6;
    const int l   = threadIdx.x & 63;
    const int l15 = l & 15;
    const int q   = l >> 4;
    const int col = w * 16 + l15;

    f16x8 bf[12];
    {
        const _Float16* wpp = WT + (size_t)col * 384 + q * 8;
#pragma unroll
        for (int c = 0; c < 12; c++) bf[c] = *(const f16x8*)(wpp + c * 32);
    }
    const float bj = bias[col];

    int t = blockIdx.x;
    if (t >= mtiles) return;
    f16x8 xf[12];
    {
        const _Float16* xp = X1 + ((size_t)t * 16 + l15) * 128 + q * 8;
        const _Float16* mp = Mt + ((size_t)t * 16 + l15) * 256 + q * 8;
#pragma unroll
        for (int c = 0; c < 4; c++) xf[c] = *(const f16x8*)(xp + c * 32);
#pragma unroll
        for (int c = 4; c < 12; c++) xf[c] = *(const f16x8*)(mp + (c - 4) * 32);
    }

    const f32x4 z4 = {0.f, 0.f, 0.f, 0.f};
    while (true) {
        int tn = t + gridDim.x;
        bool more = tn < mtiles;
        f16x8 xnf[12];
        if (more) {
            const _Float16* xp = X1 + ((size_t)tn * 16 + l15) * 128 + q * 8;
            const _Float16* mp = Mt + ((size_t)tn * 16 + l15) * 256 + q * 8;
#pragma unroll
            for (int c = 0; c < 4; c++) xnf[c] = *(const f16x8*)(xp + c * 32);
#pragma unroll
            for (int c = 4; c < 12; c++) xnf[c] = *(const f16x8*)(mp + (c - 4) * 32);
        }

        f32x4 a0 = z4;
#pragma unroll
        for (int c = 0; c < 12; c++)
            a0 = __builtin_amdgcn_mfma_f32_16x16x32_f16(xf[c], bf[c], a0, 0, 0, 0);

#pragma unroll
        for (int rg = 0; rg < 4; rg++) {
            int row = t * 16 + q * 4 + rg;
            if (row < M) X2[(size_t)row * 128 + col] = (_Float16)(a0[rg] + bj);
        }
        if (!more) break;
        t = tn;
#pragma unroll
        for (int c = 0; c < 12; c++) xf[c] = xnf[c];
    }
}

// ---------------- generic projection fallback (OUT != 3) -------------------------
__global__ __launch_bounds__(256) void proj_generic(const _Float16* __restrict__ X2,
    const _Float16* __restrict__ Mt, const float* __restrict__ wfin,
    const float* __restrict__ bfin, float* __restrict__ out, int N, int OUT)
{
    int row = blockIdx.x * 4 + (threadIdx.x >> 6);
    int l = threadIdx.x & 63;
    if (row >= N) return;
    float xv[6];
#pragma unroll
    for (int i = 0; i < 6; i++) {
        int k = l * 6 + i;
        xv[i] = (k < 128) ? (float)X2[(size_t)row * 128 + k]
                          : (float)Mt[(size_t)row * 256 + (k - 128)];
    }
    for (int c = 0; c < OUT; c++) {
        float p = 0.f;
#pragma unroll
        for (int i = 0; i < 6; i++) p += xv[i] * wfin[(size_t)(l * 6 + i) * OUT + c];
        for (int off = 32; off > 0; off >>= 1) p += __shfl_down(p, off);
        if (l == 0) out[(size_t)row * OUT + c] = p + bfin[c];
    }
}

extern "C" void kernel_launch(void* const* d_in, const int* in_sizes, int n_in,
                              void* d_out, int out_size, void* d_ws, size_t ws_size,
                              hipStream_t stream) {
    const float* feature = (const float*)d_in[0];
    const int*   ei      = (const int*)d_in[1];   // [2,E]: src then dst
    const int*   et      = (const int*)d_in[2];   // [E]
    const float* w_in    = (const float*)d_in[3];
    const float* b_in    = (const float*)d_in[4];
    const float* w_rel   = (const float*)d_in[5];
    const float* w_root  = (const float*)d_in[6];
    const float* b_conv  = (const float*)d_in[7];
    const float* w_out   = (const float*)d_in[8];
    const float* b_out   = (const float*)d_in[9];

    const int HH   = in_sizes[4];                 // 128
    const int D_IN = in_sizes[3] / HH;            // 768
    const int N    = in_sizes[0] / D_IN;          // 50000
    const int E    = in_sizes[1] / 2;             // 600000
    const int OUT  = in_sizes[9];                 // 3

    // workspace layout (16B-aligned segments)
    char* base = (char*)d_ws;
    _Float16* wInT  = (_Float16*)base;                             // 768*128 packed
    _Float16* wcatT = wInT + (size_t)D_IN * HH;                    // 128*384
    _Float16* X1    = wcatT + (size_t)HH * 384;                    // N*128
    _Float16* X2    = X1 + (size_t)N * HH;                         // N*128
    _Float16* Mt    = X2 + (size_t)N * HH;                         // N*256 (fallback only)
    float* wfin     = (float*)(Mt + (size_t)N * 256);              // 3*128*OUT
    float* bfin     = wfin + (size_t)3 * HH * (OUT > 0 ? OUT : 1); // OUT
    int* cnt        = (int*)(bfin + ((OUT + 3) & ~3));             // 2N
    int* elist      = cnt + (size_t)2 * N;                         // 2N*CAP

    hipMemsetAsync(cnt, 0, sizeof(int) * (size_t)2 * N, stream);
    {
        int ptot = D_IN * HH + HH * 384 + 3 * HH * OUT + OUT;
        prep_all<<<(ptot + 255) / 256, 256, 0, stream>>>(
            w_in, w_root, w_rel, b_conv, w_out, b_out,
            wInT, wcatT, wfin, bfin, D_IN, OUT);
    }

    // combined launch: GEMM tiles first (long pole), hist blocks overlapped behind
    const int gemmBlocks = (N + 63) / 64;
    const int histBlocks = (E + 255) / 256;
    gemm_hist<<<gemmBlocks + histBlocks, 256, 0, stream>>>(
        feature, wInT, b_in, X1, N, D_IN, HH, gemmBlocks,
        ei, ei + E, et, cnt, elist, E, N);

    const int mtiles  = (N + 15) / 16;
    const int gblocks = (N + 3) / 4;

    if (OUT == 3) {
        // layer 1: fused gather+concat-GEMM; layer 2: fused gather+projection
        fused_l1<<<mtiles, 256, 0, stream>>>(X1, wcatT, b_conv, elist, cnt, X2, N);
        gather_k<1><<<gblocks, 256, 0, stream>>>(X2, 128, nullptr, elist, cnt, N,
                                                 wfin, bfin, (float*)d_out);
    } else {
        gather_k<0><<<gblocks, 256, 0, stream>>>(X1, 128, Mt, elist, cnt, N,
                                                 nullptr, nullptr, nullptr);
        gemm_cat<<<1024, 512, 0, stream>>>(X1, Mt, wcatT, b_conv, X2, N, mtiles);
        gather_k<0><<<gblocks, 256, 0, stream>>>(X2, 128, Mt, elist, cnt, N,
                                                 nullptr, nullptr, nullptr);
        proj_generic<<<gblocks, 256, 0, stream>>>(X2, Mt, wfin, bfin,
                                                  (float*)d_out, N, OUT);
    }
}